// Round 8
// baseline (208.873 us; speedup 1.0000x reference)
//
#include <hip/hip_runtime.h>
#include <cstdint>
#include <math.h>

// ---------------------------------------------------------------------------
// BigBird attention, MI355X. B=2, S=2048, E=1024, H=16, D=64, BLOCK=64, NB=32.
// Pipeline: fused fp32->bf16 cvt -> fused QKV GEMM (dual-panel BK=64, bf16
// MFMA; V head writes transposed Vt directly) -> block-sparse flash attention
// (ds_write staging, stride-72 LDS, no-max softmax) -> out-proj GEMM
// (64x128 tiles, 2 wgs/CU, dual-panel).
// R8: K=1024 gives only 32 BK=32 iterations -> barrier drains dominate
// (QKV at 470 TF vs m97's 874). Dual-panel staging (two lane-monotonic
// stride-32 panels per barrier) doubles MFMA/barrier without breaking the
// global_load_lds address-order constraint (R6 lesson) or the conflict-free
// stride-32 read pattern. Out-proj's 256-wg grid (1 wg/CU, no latency
// overlap) -> 64x128 tiles, 512 wgs.
// Workspace layout (40 MB):
//   [0,8M)    hs_bf16   -> reused as attn-out bf16 after QKV GEMM
//   [8M,16M)  wq/wk/wv/wo bf16 (2 MB each)
//   [16M,24M) Q bf16
//   [24M,32M) K bf16
//   [32M,40M) Vt bf16 (64 x 2048 per (b,h)) — written by QKV GEMM epilogue
// ---------------------------------------------------------------------------

#define DEVI __device__ __forceinline__

typedef __bf16 bf16x8 __attribute__((ext_vector_type(8)));
typedef float floatx4 __attribute__((ext_vector_type(4)));
typedef unsigned short u16x8 __attribute__((ext_vector_type(8)));
typedef unsigned short u16x4 __attribute__((ext_vector_type(4)));
typedef unsigned short ushort_t;

typedef const __attribute__((address_space(1))) void* gptr_as1;
typedef __attribute__((address_space(3))) void* lptr_as3;

DEVI ushort_t f2bf(float f) {  // round-to-nearest-even fp32 -> bf16
  unsigned u = __float_as_uint(f);
  unsigned r = ((u >> 16) & 1u) + 0x7fffu;
  return (ushort_t)((u + r) >> 16);
}

DEVI void lds_load16(void* lds, const void* g) {
  // async DMA global->LDS, 16B/lane; dest = uniform base + lane*16.
  // ONLY safe with lane-monotonic source addresses (R6 post-mortem).
  __builtin_amdgcn_global_load_lds((gptr_as1)g, (lptr_as3)lds, 16, 0, 0);
}

DEVI floatx4 mfma16(bf16x8 a, bf16x8 b, floatx4 c) {
  return __builtin_amdgcn_mfma_f32_16x16x32_bf16(a, b, c, 0, 0, 0);
}

// ---------------------------------------------------------------------------
// Compile-time BigBird block mask (exact numpy legacy RandomState(0) MT19937
// replication — verified vs reference in round 1). Compacted to per-row
// active-block lists. Unused list slots are 0 (safe to load, results unused).
// ---------------------------------------------------------------------------
struct MTState { unsigned mt[624]; int mti; };

constexpr unsigned mt_next(MTState& s) {
  if (s.mti >= 624) {
    for (int k = 0; k < 624; ++k) {
      unsigned y = (s.mt[k] & 0x80000000u) | (s.mt[(k + 1) % 624] & 0x7fffffffu);
      unsigned v = s.mt[(k + 397) % 624] ^ (y >> 1);
      if (y & 1u) v ^= 0x9908b0dfu;
      s.mt[k] = v;
    }
    s.mti = 0;
  }
  unsigned y = s.mt[s.mti++];
  y ^= y >> 11;
  y ^= (y << 7) & 0x9d2c5680u;
  y ^= (y << 15) & 0xefc60000u;
  y ^= y >> 18;
  return y;
}

constexpr unsigned mt_interval(MTState& s, unsigned mx) {  // uniform in [0,mx]
  if (mx == 0u) return 0u;
  unsigned msk = mx;
  msk |= msk >> 1; msk |= msk >> 2; msk |= msk >> 4; msk |= msk >> 8; msk |= msk >> 16;
  unsigned v = mt_next(s) & msk;
  while (v > mx) v = mt_next(s) & msk;
  return v;
}

struct MaskPack { unsigned char list[32][32]; int cnt[32]; };

constexpr MaskPack make_pack() {
  unsigned char m[32][32] = {};
  for (int i = 0; i < 32; ++i)
    for (int j = 0; j < 32; ++j) {
      int d = i - j; if (d < 0) d = -d;
      m[i][j] = (i == 0 || j == 0 || d <= 3) ? (unsigned char)1 : (unsigned char)0;
    }
  MTState st{};
  st.mt[0] = 0u;
  for (int i = 1; i < 624; ++i)
    st.mt[i] = 1812433253u * (st.mt[i - 1] ^ (st.mt[i - 1] >> 30)) + (unsigned)i;
  st.mti = 624;
  for (int b = 1; b < 32; ++b) {
    int avail[32] = {}; int n = 0;
    for (int x = 1; x < 32; ++x) {
      int d = x - b; if (d < 0) d = -d;
      if (d > 3) avail[n++] = x;
    }
    if (n == 0) continue;
    int perm[32] = {};
    for (int i = 0; i < n; ++i) perm[i] = i;
    for (int i = n - 1; i > 0; --i) {
      unsigned j = mt_interval(st, (unsigned)i);
      int t = perm[i]; perm[i] = perm[(int)j]; perm[(int)j] = t;
    }
    int take = n < 3 ? n : 3;
    for (int s = 0; s < take; ++s) m[b][avail[perm[s]]] = 1;
  }
  MaskPack P{};
  for (int i = 0; i < 32; ++i) {
    int c = 0;
    for (int j = 0; j < 32; ++j)
      if (m[i][j]) P.list[i][c++] = (unsigned char)j;
    P.cnt[i] = c;
  }
  return P;
}

__constant__ MaskPack MP = make_pack();

// ---------------------------------------------------------------------------
// Fused fp32 -> bf16 conversion for hs + 4 weight matrices, 4 el/thread.
// ---------------------------------------------------------------------------
__global__ __launch_bounds__(256) void cvt_all(
    const float* __restrict__ hs, const float* __restrict__ wq,
    const float* __restrict__ wk, const float* __restrict__ wv,
    const float* __restrict__ wo,
    ushort_t* __restrict__ hs_bf, ushort_t* __restrict__ wq_bf,
    ushort_t* __restrict__ wk_bf, ushort_t* __restrict__ wv_bf,
    ushort_t* __restrict__ wo_bf) {
  const int i = blockIdx.x * 256 + threadIdx.x;
  const float* s;
  ushort_t* d;
  int j;
  if (i < 1048576) {
    s = hs; d = hs_bf; j = i;
  } else {
    const int t = (i - 1048576) >> 18;
    j = (i - 1048576) & 262143;
    s = t == 0 ? wq : (t == 1 ? wk : (t == 2 ? wv : wo));
    d = t == 0 ? wq_bf : (t == 1 ? wk_bf : (t == 2 ? wv_bf : wo_bf));
  }
  const float4 f = ((const float4*)s)[j];
  u16x4 o;
  o.x = f2bf(f.x); o.y = f2bf(f.y); o.z = f2bf(f.z); o.w = f2bf(f.w);
  ((u16x4*)d)[j] = o;
}

// ---------------------------------------------------------------------------
// Fused QKV GEMM: C[m][n] = sum_k A[m][k]*W[n][k] + bias[n]. M=4096, N=K=1024.
// 128x128 tile, dual-panel BK=64 (two lane-monotonic stride-32 panels staged
// per barrier -> 32 MFMA/barrier), 256 threads, global_load_lds width-16.
// blockIdx.z selects (W, bias, out); z==2 writes the transposed Vt layout.
// ---------------------------------------------------------------------------
__global__ __launch_bounds__(256) void gemm_qkv(
    const ushort_t* __restrict__ A,
    const ushort_t* __restrict__ W0, const ushort_t* __restrict__ W1, const ushort_t* __restrict__ W2,
    const float* __restrict__ b0, const float* __restrict__ b1, const float* __restrict__ b2,
    void* __restrict__ o0, void* __restrict__ o1, void* __restrict__ o2) {
  constexpr int N = 1024, K = 1024;
  __shared__ alignas(16) ushort_t As[2][128 * 32];
  __shared__ alignas(16) ushort_t Bs[2][128 * 32];
  const int z = blockIdx.z;
  const ushort_t* Bw = z == 0 ? W0 : (z == 1 ? W1 : W2);
  const float* bias = z == 0 ? b0 : (z == 1 ? b1 : b2);
  void* Cout = z == 0 ? o0 : (z == 1 ? o1 : o2);

  const int tid = threadIdx.x;
  const int w = tid >> 6, l = tid & 63, quad = l >> 4, li = l & 15;
  const int m0 = blockIdx.y * 128, n0 = blockIdx.x * 128;
  const int wm = (w >> 1) * 64, wn = (w & 1) * 64;

  const int lof0 = (w * 2 + 0) * 512 + l * 8;
  const int lof1 = (w * 2 + 1) * 512 + l * 8;
  const int rA0 = lof0 >> 5, cA0 = lof0 & 31;
  const int rA1 = lof1 >> 5, cA1 = lof1 & 31;
  const ushort_t* gA0 = A + (size_t)(m0 + rA0) * K + cA0;
  const ushort_t* gA1 = A + (size_t)(m0 + rA1) * K + cA1;
  const ushort_t* gB0 = Bw + (size_t)(n0 + rA0) * K + cA0;
  const ushort_t* gB1 = Bw + (size_t)(n0 + rA1) * K + cA1;

  const floatx4 fzero = {0.0f, 0.0f, 0.0f, 0.0f};
  floatx4 acc[4][4];
#pragma unroll
  for (int i = 0; i < 4; ++i)
#pragma unroll
    for (int j = 0; j < 4; ++j) acc[i][j] = fzero;

  for (int k0 = 0; k0 < K; k0 += 64) {
#pragma unroll
    for (int p = 0; p < 2; ++p) {
      lds_load16(As[p] + lof0, gA0 + k0 + p * 32);
      lds_load16(As[p] + lof1, gA1 + k0 + p * 32);
      lds_load16(Bs[p] + lof0, gB0 + k0 + p * 32);
      lds_load16(Bs[p] + lof1, gB1 + k0 + p * 32);
    }
    __syncthreads();
#pragma unroll
    for (int p = 0; p < 2; ++p) {
      bf16x8 af[4], bfr[4];
#pragma unroll
      for (int mi = 0; mi < 4; ++mi)
        af[mi] = *(const bf16x8*)(As[p] + (wm + mi * 16 + li) * 32 + quad * 8);
#pragma unroll
      for (int ni = 0; ni < 4; ++ni)
        bfr[ni] = *(const bf16x8*)(Bs[p] + (wn + ni * 16 + li) * 32 + quad * 8);
#pragma unroll
      for (int mi = 0; mi < 4; ++mi)
#pragma unroll
        for (int ni = 0; ni < 4; ++ni)
          acc[mi][ni] = mfma16(af[mi], bfr[ni], acc[mi][ni]);
    }
    __syncthreads();
  }

  if (z == 2) {
    // V head: write transposed Vt[((b*16+h)*64+d)*2048 + s], pack 4 rows (s)
    ushort_t* Vt = (ushort_t*)Cout;
#pragma unroll
    for (int ni = 0; ni < 4; ++ni) {
      const int col = n0 + wn + ni * 16 + li;  // = h*64 + d
      const float bv = bias[col];
      const int hh = col >> 6, dd = col & 63;
#pragma unroll
      for (int mi = 0; mi < 4; ++mi) {
        const int row0 = m0 + wm + mi * 16 + quad * 4;  // = b*2048 + s0
        const int bb = row0 >> 11, s0 = row0 & 2047;
        u16x4 pk;
#pragma unroll
        for (int r = 0; r < 4; ++r) pk[r] = f2bf(acc[mi][ni][r] + bv);
        *(u16x4*)(Vt + (size_t)((bb * 16 + hh) * 64 + dd) * 2048 + s0) = pk;
      }
    }
  } else {
#pragma unroll
    for (int ni = 0; ni < 4; ++ni) {
      const int col = n0 + wn + ni * 16 + li;
      const float bv = bias[col];
#pragma unroll
      for (int mi = 0; mi < 4; ++mi) {
#pragma unroll
        for (int r = 0; r < 4; ++r) {
          const int row = m0 + wm + mi * 16 + quad * 4 + r;
          ((ushort_t*)Cout)[(size_t)row * N + col] = f2bf(acc[mi][ni][r] + bv);
        }
      }
    }
  }
}

// ---------------------------------------------------------------------------
// Out-proj GEMM: C[m][n] = sum_k A[m][k]*Wo[n][k] + bias[n], fp32 out.
// 64x128 tiles -> grid (8, 64) = 512 wgs = 2 wgs/CU (the 128-tile version's
// 256-wg grid gave 1 wg/CU: zero cross-wg latency hiding). Dual-panel BK=64.
// Wave w: wm=(w>>1)*32, wn=(w&1)*64; acc 2x4 of 16x16 tiles.
// ---------------------------------------------------------------------------
__global__ __launch_bounds__(256) void gemm_o64(
    const ushort_t* __restrict__ A, const ushort_t* __restrict__ W,
    const float* __restrict__ bias, float* __restrict__ C) {
  constexpr int N = 1024, K = 1024;
  __shared__ alignas(16) ushort_t As[2][64 * 32];
  __shared__ alignas(16) ushort_t Bs[2][128 * 32];
  const int tid = threadIdx.x;
  const int w = tid >> 6, l = tid & 63, quad = l >> 4, li = l & 15;
  const int m0 = blockIdx.y * 64, n0 = blockIdx.x * 128;
  const int wm = (w >> 1) * 32, wn = (w & 1) * 64;

  // staging: A 64x32 = 4 calls (1/wave); B 128x32 = 8 calls (2/wave)
  const int lofA = w * 512 + l * 8;
  const int rA = lofA >> 5, cA = lofA & 31;
  const int lofB0 = (w * 2 + 0) * 512 + l * 8;
  const int lofB1 = (w * 2 + 1) * 512 + l * 8;
  const int rB0 = lofB0 >> 5, cB0 = lofB0 & 31;
  const int rB1 = lofB1 >> 5, cB1 = lofB1 & 31;
  const ushort_t* gA = A + (size_t)(m0 + rA) * K + cA;
  const ushort_t* gB0 = W + (size_t)(n0 + rB0) * K + cB0;
  const ushort_t* gB1 = W + (size_t)(n0 + rB1) * K + cB1;

  const floatx4 fzero = {0.0f, 0.0f, 0.0f, 0.0f};
  floatx4 acc[2][4];
#pragma unroll
  for (int i = 0; i < 2; ++i)
#pragma unroll
    for (int j = 0; j < 4; ++j) acc[i][j] = fzero;

  for (int k0 = 0; k0 < K; k0 += 64) {
#pragma unroll
    for (int p = 0; p < 2; ++p) {
      lds_load16(As[p] + lofA, gA + k0 + p * 32);
      lds_load16(Bs[p] + lofB0, gB0 + k0 + p * 32);
      lds_load16(Bs[p] + lofB1, gB1 + k0 + p * 32);
    }
    __syncthreads();
#pragma unroll
    for (int p = 0; p < 2; ++p) {
      bf16x8 af[2], bfr[4];
#pragma unroll
      for (int mi = 0; mi < 2; ++mi)
        af[mi] = *(const bf16x8*)(As[p] + (wm + mi * 16 + li) * 32 + quad * 8);
#pragma unroll
      for (int ni = 0; ni < 4; ++ni)
        bfr[ni] = *(const bf16x8*)(Bs[p] + (wn + ni * 16 + li) * 32 + quad * 8);
#pragma unroll
      for (int mi = 0; mi < 2; ++mi)
#pragma unroll
        for (int ni = 0; ni < 4; ++ni)
          acc[mi][ni] = mfma16(af[mi], bfr[ni], acc[mi][ni]);
    }
    __syncthreads();
  }

#pragma unroll
  for (int ni = 0; ni < 4; ++ni) {
    const int col = n0 + wn + ni * 16 + li;
    const float bv = bias[col];
#pragma unroll
    for (int mi = 0; mi < 2; ++mi) {
#pragma unroll
      for (int r = 0; r < 4; ++r) {
        const int row = m0 + wm + mi * 16 + quad * 4 + r;
        C[(size_t)row * N + col] = acc[mi][ni][r] + bv;
      }
    }
  }
}

// ---------------------------------------------------------------------------
// Block-sparse flash attention, ds_write staging, no-max softmax (unchanged
// from R7 — passed at absmax 2.2e-3, no longer the top dispatch).
// Grid (hb=b*16+h : 32, qb : 32); 256 threads, 4 waves.
// ---------------------------------------------------------------------------
__global__ __launch_bounds__(256) void attn_kernel(
    const ushort_t* __restrict__ Q, const ushort_t* __restrict__ Kg,
    const ushort_t* __restrict__ Vtg, ushort_t* __restrict__ O) {
  __shared__ alignas(16) ushort_t Kls[64 * 72];   // 9 KB, padded stride 72
  __shared__ alignas(16) ushort_t Vls[64 * 72];   // 9 KB
  __shared__ alignas(16) ushort_t Ps[4][16 * 72]; // 9 KB, per-wave P transpose

  const int tid = threadIdx.x;
  const int w = tid >> 6, l = tid & 63, quad = l >> 4, li = l & 15;
  const int hb = blockIdx.x, qb = blockIdx.y;
  const int h = hb & 15, b = hb >> 4;
  const size_t qoff = (size_t)b * 2048 * 1024 + (size_t)h * 64;
  const size_t vtoff = (size_t)hb * 64 * 2048;

  // mask list -> 8 uniform regs; kb extracted by rolling byte shifts
  unsigned lw[8];
#pragma unroll
  for (int j = 0; j < 8; ++j) lw[j] = ((const unsigned*)(MP.list[qb]))[j];
  const int nact = MP.cnt[qb];
  auto roll = [&]() -> int {
    const int kb = (int)(lw[0] & 255u);
#pragma unroll
    for (int j = 0; j < 7; ++j) lw[j] = (lw[j] >> 8) | (lw[j + 1] << 24);
    lw[7] >>= 8;
    return kb;
  };

  // Q fragments (A-layout), pre-scaled by 2^-3 (exact in bf16)
  const int qrow = qb * 64 + w * 16 + li;
  bf16x8 aq0 = *(const bf16x8*)(Q + qoff + (size_t)qrow * 1024 + quad * 8);
  bf16x8 aq1 = *(const bf16x8*)(Q + qoff + (size_t)qrow * 1024 + 32 + quad * 8);
#pragma unroll
  for (int j = 0; j < 8; ++j) {
    aq0[j] = (__bf16)((float)aq0[j] * 0.125f);
    aq1[j] = (__bf16)((float)aq1[j] * 0.125f);
  }

  const floatx4 fzero = {0.0f, 0.0f, 0.0f, 0.0f};
  floatx4 o_acc[4];
  float lp[4];
#pragma unroll
  for (int nt = 0; nt < 4; ++nt) o_acc[nt] = fzero;
#pragma unroll
  for (int r = 0; r < 4; ++r) lp[r] = 0.0f;

  // staging geometry: thread handles rows r0 = w*16 + (l>>3), r1 = r0+8,
  // colblock cb = (l&7)*8; lanes 0..7 = one contiguous 128B run per row.
  const int r0 = w * 16 + (l >> 3);
  const int r1 = r0 + 8;
  const int cb = (l & 7) * 8;
  const ushort_t* kg0 = Kg + qoff + (size_t)r0 * 1024 + cb;
  const ushort_t* kg1 = Kg + qoff + (size_t)r1 * 1024 + cb;
  const ushort_t* vg0 = Vtg + vtoff + (size_t)r0 * 2048 + cb;
  const ushort_t* vg1 = Vtg + vtoff + (size_t)r1 * 2048 + cb;
  ushort_t* kd0 = Kls + r0 * 72 + cb;
  ushort_t* kd1 = Kls + r1 * 72 + cb;
  ushort_t* vd0 = Vls + r0 * 72 + cb;
  ushort_t* vd1 = Vls + r1 * 72 + cb;
  ushort_t* PsW = Ps[w];

  int kb = roll();
  {
    const u16x8 a0 = *(const u16x8*)(kg0 + (size_t)kb * 65536);
    const u16x8 a1 = *(const u16x8*)(kg1 + (size_t)kb * 65536);
    const u16x8 b0 = *(const u16x8*)(vg0 + kb * 64);
    const u16x8 b1 = *(const u16x8*)(vg1 + kb * 64);
    *(u16x8*)kd0 = a0; *(u16x8*)kd1 = a1;
    *(u16x8*)vd0 = b0; *(u16x8*)vd1 = b1;
  }

  for (int i = 0; i < nact; ++i) {
    const int kbn = (i + 1 < nact) ? roll() : 0;
    __syncthreads();  // staging visible to all waves

    // S = (Q/8) K^T  (C-layout: row q = quad*4+r, col key = nt*16+li)
    floatx4 s[4];
#pragma unroll
    for (int nt = 0; nt < 4; ++nt) {
      const bf16x8 bk0 = *(const bf16x8*)(Kls + (nt * 16 + li) * 72 + quad * 8);
      const bf16x8 bk1 = *(const bf16x8*)(Kls + (nt * 16 + li) * 72 + 32 + quad * 8);
      s[nt] = mfma16(aq1, bk1, mfma16(aq0, bk0, fzero));
    }

    // P = exp(S) — no max subtraction (unit-variance scores, fp32-safe);
    // accumulate per-lane denominator partials; P -> per-wave LDS (A-layout)
#pragma unroll
    for (int nt = 0; nt < 4; ++nt)
#pragma unroll
      for (int r = 0; r < 4; ++r) {
        const float e = __expf(s[nt][r]);
        lp[r] += e;
        PsW[(quad * 4 + r) * 72 + nt * 16 + li] = f2bf(e);
      }

    // O += P V  (P A-frag via per-wave LDS, in-order DS pipe, no barrier)
#pragma unroll
    for (int c = 0; c < 2; ++c) {
      const bf16x8 pa = *(const bf16x8*)(PsW + li * 72 + c * 32 + quad * 8);
#pragma unroll
      for (int nt = 0; nt < 4; ++nt) {
        const bf16x8 vb = *(const bf16x8*)(Vls + (nt * 16 + li) * 72 + c * 32 + quad * 8);
        o_acc[nt] = mfma16(pa, vb, o_acc[nt]);
      }
    }

    __syncthreads();  // all waves done reading Kls/Vls
    if (i + 1 < nact) {
      const u16x8 a0 = *(const u16x8*)(kg0 + (size_t)kbn * 65536);
      const u16x8 a1 = *(const u16x8*)(kg1 + (size_t)kbn * 65536);
      const u16x8 b0 = *(const u16x8*)(vg0 + kbn * 64);
      const u16x8 b1 = *(const u16x8*)(vg1 + kbn * 64);
      *(u16x8*)kd0 = a0; *(u16x8*)kd1 = a1;
      *(u16x8*)vd0 = b0; *(u16x8*)vd1 = b1;
    }
  }

  // denominator: reduce the 16 lanes holding each row's column partials
#pragma unroll
  for (int stp = 1; stp <= 8; stp <<= 1)
#pragma unroll
    for (int r = 0; r < 4; ++r) lp[r] += __shfl_xor(lp[r], stp);

  // epilogue: O[b][s][h*64+d] bf16
#pragma unroll
  for (int r = 0; r < 4; ++r) {
    const float rinv = 1.0f / lp[r];
#pragma unroll
    for (int nt = 0; nt < 4; ++nt) {
      const float ov = o_acc[nt][r] * rinv;
      O[qoff + (size_t)(qb * 64 + w * 16 + quad * 4 + r) * 1024 + nt * 16 + li] = f2bf(ov);
    }
  }
}

// ---------------------------------------------------------------------------
extern "C" void kernel_launch(void* const* d_in, const int* in_sizes, int n_in,
                              void* d_out, int out_size, void* d_ws, size_t ws_size,
                              hipStream_t stream) {
  const float* hs = (const float*)d_in[0];
  const float* wq = (const float*)d_in[1];
  const float* bq = (const float*)d_in[2];
  const float* wk = (const float*)d_in[3];
  const float* bk = (const float*)d_in[4];
  const float* wv = (const float*)d_in[5];
  const float* bv = (const float*)d_in[6];
  const float* wo = (const float*)d_in[7];
  const float* bo = (const float*)d_in[8];
  float* out = (float*)d_out;

  char* ws = (char*)d_ws;
  ushort_t* hs_bf = (ushort_t*)(ws);                 // 8 MB; reused as attn out
  ushort_t* wq_bf = (ushort_t*)(ws + (8ull << 20));  // 2 MB each
  ushort_t* wk_bf = (ushort_t*)(ws + (10ull << 20));
  ushort_t* wv_bf = (ushort_t*)(ws + (12ull << 20));
  ushort_t* wo_bf = (ushort_t*)(ws + (14ull << 20));
  ushort_t* Qb = (ushort_t*)(ws + (16ull << 20));    // 8 MB each
  ushort_t* Kb = (ushort_t*)(ws + (24ull << 20));
  ushort_t* Vt = (ushort_t*)(ws + (32ull << 20));    // transposed V
  ushort_t* AO = hs_bf;  // hs_bf dead after QKV GEMM

  cvt_all<<<8192, 256, 0, stream>>>(hs, wq, wk, wv, wo,
                                    hs_bf, wq_bf, wk_bf, wv_bf, wo_bf);

  dim3 gq(8, 32, 3);  // fused Q,K,V projections; z==2 writes Vt transposed
  gemm_qkv<<<gq, 256, 0, stream>>>(hs_bf, wq_bf, wk_bf, wv_bf, bq, bk, bv, Qb, Kb, Vt);

  dim3 ga(32, 32, 1);  // x = b*16+h (XCD-resident K/V), y = qb
  attn_kernel<<<ga, 256, 0, stream>>>(Qb, Kb, Vt, AO);

  dim3 go(8, 64, 1);   // 64x128 tiles, 512 wgs = 2 wgs/CU
  gemm_o64<<<go, 256, 0, stream>>>(AO, wo_bf, bo, out);
}

// Round 9
// 197.630 us; speedup vs baseline: 1.0569x; 1.0569x over previous
//
#include <hip/hip_runtime.h>
#include <cstdint>
#include <math.h>

// ---------------------------------------------------------------------------
// BigBird attention, MI355X. B=2, S=2048, E=1024, H=16, D=64, BLOCK=64, NB=32.
// Pipeline: fused fp32->bf16 cvt -> fused QKV GEMM (single-panel BK=32, bf16
// MFMA; V head writes transposed Vt directly) -> block-sparse flash attention
// (ds_write staging, stride-72 LDS, no-max softmax) -> out-proj GEMM (64x128
// tiles). R9: R8's dual-panel BK=64 REGRESSED (55->68 µs, FETCH 69->101 MB,
// occupancy 14->10%): barrier drain was not the dominant term, L2 locality
// is. Reverted to single-panel; grids swizzled so x = m-tile -> XCD = x%8
// owns a 1 MB A-patch (fits per-XCD L2) reused across all n-tiles and z,
// instead of every XCD streaming the full 8 MB A.
// Workspace layout (40 MB):
//   [0,8M)    hs_bf16   -> reused as attn-out bf16 after QKV GEMM
//   [8M,16M)  wq/wk/wv/wo bf16 (2 MB each)
//   [16M,24M) Q bf16
//   [24M,32M) K bf16
//   [32M,40M) Vt bf16 (64 x 2048 per (b,h)) — written by QKV GEMM epilogue
// ---------------------------------------------------------------------------

#define DEVI __device__ __forceinline__

typedef __bf16 bf16x8 __attribute__((ext_vector_type(8)));
typedef float floatx4 __attribute__((ext_vector_type(4)));
typedef unsigned short u16x8 __attribute__((ext_vector_type(8)));
typedef unsigned short u16x4 __attribute__((ext_vector_type(4)));
typedef unsigned short ushort_t;

typedef const __attribute__((address_space(1))) void* gptr_as1;
typedef __attribute__((address_space(3))) void* lptr_as3;

DEVI ushort_t f2bf(float f) {  // round-to-nearest-even fp32 -> bf16
  unsigned u = __float_as_uint(f);
  unsigned r = ((u >> 16) & 1u) + 0x7fffu;
  return (ushort_t)((u + r) >> 16);
}

DEVI void lds_load16(void* lds, const void* g) {
  // async DMA global->LDS, 16B/lane; dest = uniform base + lane*16.
  // ONLY safe with lane-monotonic source addresses (R6 post-mortem).
  __builtin_amdgcn_global_load_lds((gptr_as1)g, (lptr_as3)lds, 16, 0, 0);
}

DEVI floatx4 mfma16(bf16x8 a, bf16x8 b, floatx4 c) {
  return __builtin_amdgcn_mfma_f32_16x16x32_bf16(a, b, c, 0, 0, 0);
}

// ---------------------------------------------------------------------------
// Compile-time BigBird block mask (exact numpy legacy RandomState(0) MT19937
// replication — verified vs reference in round 1). Compacted to per-row
// active-block lists. Unused list slots are 0 (safe to load, results unused).
// ---------------------------------------------------------------------------
struct MTState { unsigned mt[624]; int mti; };

constexpr unsigned mt_next(MTState& s) {
  if (s.mti >= 624) {
    for (int k = 0; k < 624; ++k) {
      unsigned y = (s.mt[k] & 0x80000000u) | (s.mt[(k + 1) % 624] & 0x7fffffffu);
      unsigned v = s.mt[(k + 397) % 624] ^ (y >> 1);
      if (y & 1u) v ^= 0x9908b0dfu;
      s.mt[k] = v;
    }
    s.mti = 0;
  }
  unsigned y = s.mt[s.mti++];
  y ^= y >> 11;
  y ^= (y << 7) & 0x9d2c5680u;
  y ^= (y << 15) & 0xefc60000u;
  y ^= y >> 18;
  return y;
}

constexpr unsigned mt_interval(MTState& s, unsigned mx) {  // uniform in [0,mx]
  if (mx == 0u) return 0u;
  unsigned msk = mx;
  msk |= msk >> 1; msk |= msk >> 2; msk |= msk >> 4; msk |= msk >> 8; msk |= msk >> 16;
  unsigned v = mt_next(s) & msk;
  while (v > mx) v = mt_next(s) & msk;
  return v;
}

struct MaskPack { unsigned char list[32][32]; int cnt[32]; };

constexpr MaskPack make_pack() {
  unsigned char m[32][32] = {};
  for (int i = 0; i < 32; ++i)
    for (int j = 0; j < 32; ++j) {
      int d = i - j; if (d < 0) d = -d;
      m[i][j] = (i == 0 || j == 0 || d <= 3) ? (unsigned char)1 : (unsigned char)0;
    }
  MTState st{};
  st.mt[0] = 0u;
  for (int i = 1; i < 624; ++i)
    st.mt[i] = 1812433253u * (st.mt[i - 1] ^ (st.mt[i - 1] >> 30)) + (unsigned)i;
  st.mti = 624;
  for (int b = 1; b < 32; ++b) {
    int avail[32] = {}; int n = 0;
    for (int x = 1; x < 32; ++x) {
      int d = x - b; if (d < 0) d = -d;
      if (d > 3) avail[n++] = x;
    }
    if (n == 0) continue;
    int perm[32] = {};
    for (int i = 0; i < n; ++i) perm[i] = i;
    for (int i = n - 1; i > 0; --i) {
      unsigned j = mt_interval(st, (unsigned)i);
      int t = perm[i]; perm[i] = perm[(int)j]; perm[(int)j] = t;
    }
    int take = n < 3 ? n : 3;
    for (int s = 0; s < take; ++s) m[b][avail[perm[s]]] = 1;
  }
  MaskPack P{};
  for (int i = 0; i < 32; ++i) {
    int c = 0;
    for (int j = 0; j < 32; ++j)
      if (m[i][j]) P.list[i][c++] = (unsigned char)j;
    P.cnt[i] = c;
  }
  return P;
}

__constant__ MaskPack MP = make_pack();

// ---------------------------------------------------------------------------
// Fused fp32 -> bf16 conversion for hs + 4 weight matrices, 4 el/thread.
// ---------------------------------------------------------------------------
__global__ __launch_bounds__(256) void cvt_all(
    const float* __restrict__ hs, const float* __restrict__ wq,
    const float* __restrict__ wk, const float* __restrict__ wv,
    const float* __restrict__ wo,
    ushort_t* __restrict__ hs_bf, ushort_t* __restrict__ wq_bf,
    ushort_t* __restrict__ wk_bf, ushort_t* __restrict__ wv_bf,
    ushort_t* __restrict__ wo_bf) {
  const int i = blockIdx.x * 256 + threadIdx.x;
  const float* s;
  ushort_t* d;
  int j;
  if (i < 1048576) {
    s = hs; d = hs_bf; j = i;
  } else {
    const int t = (i - 1048576) >> 18;
    j = (i - 1048576) & 262143;
    s = t == 0 ? wq : (t == 1 ? wk : (t == 2 ? wv : wo));
    d = t == 0 ? wq_bf : (t == 1 ? wk_bf : (t == 2 ? wv_bf : wo_bf));
  }
  const float4 f = ((const float4*)s)[j];
  u16x4 o;
  o.x = f2bf(f.x); o.y = f2bf(f.y); o.z = f2bf(f.z); o.w = f2bf(f.w);
  ((u16x4*)d)[j] = o;
}

// ---------------------------------------------------------------------------
// Fused QKV GEMM: C[m][n] = sum_k A[m][k]*W[n][k] + bias[n]. M=4096, N=K=1024.
// 128x128 tile, BK=32 single-panel (R7-proven), 256 threads, global_load_lds
// width-16. Grid (x=m-tile 32, y=n-tile 8, z=matrix 3): XCD = x%8 owns 4
// m-tile rows (1 MB A-patch, L2-resident, reused 24x). z==2 writes Vt.
// ---------------------------------------------------------------------------
__global__ __launch_bounds__(256) void gemm_qkv(
    const ushort_t* __restrict__ A,
    const ushort_t* __restrict__ W0, const ushort_t* __restrict__ W1, const ushort_t* __restrict__ W2,
    const float* __restrict__ b0, const float* __restrict__ b1, const float* __restrict__ b2,
    void* __restrict__ o0, void* __restrict__ o1, void* __restrict__ o2) {
  constexpr int N = 1024, K = 1024;
  __shared__ alignas(16) ushort_t As[128 * 32];
  __shared__ alignas(16) ushort_t Bs[128 * 32];
  const int z = blockIdx.z;
  const ushort_t* Bw = z == 0 ? W0 : (z == 1 ? W1 : W2);
  const float* bias = z == 0 ? b0 : (z == 1 ? b1 : b2);
  void* Cout = z == 0 ? o0 : (z == 1 ? o1 : o2);

  const int tid = threadIdx.x;
  const int w = tid >> 6, l = tid & 63, quad = l >> 4, li = l & 15;
  const int m0 = blockIdx.x * 128, n0 = blockIdx.y * 128;  // x = m-tile (XCD)
  const int wm = (w >> 1) * 64, wn = (w & 1) * 64;

  const int lof0 = (w * 2 + 0) * 512 + l * 8;
  const int lof1 = (w * 2 + 1) * 512 + l * 8;
  const int rA0 = lof0 >> 5, cA0 = lof0 & 31;
  const int rA1 = lof1 >> 5, cA1 = lof1 & 31;
  const ushort_t* gA0 = A + (size_t)(m0 + rA0) * K + cA0;
  const ushort_t* gA1 = A + (size_t)(m0 + rA1) * K + cA1;
  const ushort_t* gB0 = Bw + (size_t)(n0 + rA0) * K + cA0;
  const ushort_t* gB1 = Bw + (size_t)(n0 + rA1) * K + cA1;

  const floatx4 fzero = {0.0f, 0.0f, 0.0f, 0.0f};
  floatx4 acc[4][4];
#pragma unroll
  for (int i = 0; i < 4; ++i)
#pragma unroll
    for (int j = 0; j < 4; ++j) acc[i][j] = fzero;

  for (int k0 = 0; k0 < K; k0 += 32) {
    lds_load16(As + lof0, gA0 + k0);
    lds_load16(As + lof1, gA1 + k0);
    lds_load16(Bs + lof0, gB0 + k0);
    lds_load16(Bs + lof1, gB1 + k0);
    __syncthreads();
    bf16x8 af[4], bfr[4];
#pragma unroll
    for (int mi = 0; mi < 4; ++mi)
      af[mi] = *(const bf16x8*)(As + (wm + mi * 16 + li) * 32 + quad * 8);
#pragma unroll
    for (int ni = 0; ni < 4; ++ni)
      bfr[ni] = *(const bf16x8*)(Bs + (wn + ni * 16 + li) * 32 + quad * 8);
#pragma unroll
    for (int mi = 0; mi < 4; ++mi)
#pragma unroll
      for (int ni = 0; ni < 4; ++ni)
        acc[mi][ni] = mfma16(af[mi], bfr[ni], acc[mi][ni]);
    __syncthreads();
  }

  if (z == 2) {
    // V head: write transposed Vt[((b*16+h)*64+d)*2048 + s], pack 4 rows (s)
    ushort_t* Vt = (ushort_t*)Cout;
#pragma unroll
    for (int ni = 0; ni < 4; ++ni) {
      const int col = n0 + wn + ni * 16 + li;  // = h*64 + d
      const float bv = bias[col];
      const int hh = col >> 6, dd = col & 63;
#pragma unroll
      for (int mi = 0; mi < 4; ++mi) {
        const int row0 = m0 + wm + mi * 16 + quad * 4;  // = b*2048 + s0
        const int bb = row0 >> 11, s0 = row0 & 2047;
        u16x4 pk;
#pragma unroll
        for (int r = 0; r < 4; ++r) pk[r] = f2bf(acc[mi][ni][r] + bv);
        *(u16x4*)(Vt + (size_t)((bb * 16 + hh) * 64 + dd) * 2048 + s0) = pk;
      }
    }
  } else {
#pragma unroll
    for (int ni = 0; ni < 4; ++ni) {
      const int col = n0 + wn + ni * 16 + li;
      const float bv = bias[col];
#pragma unroll
      for (int mi = 0; mi < 4; ++mi) {
#pragma unroll
        for (int r = 0; r < 4; ++r) {
          const int row = m0 + wm + mi * 16 + quad * 4 + r;
          ((ushort_t*)Cout)[(size_t)row * N + col] = f2bf(acc[mi][ni][r] + bv);
        }
      }
    }
  }
}

// ---------------------------------------------------------------------------
// Out-proj GEMM: C[m][n] = sum_k A[m][k]*Wo[n][k] + bias[n], fp32 out.
// 64x128 tiles, grid (x=m-tile 64, y=n-tile 8) = 512 wgs = 2 wgs/CU;
// XCD = x%8 owns 8 m-tile rows (1 MB A-patch). Single-panel BK=32.
// ---------------------------------------------------------------------------
__global__ __launch_bounds__(256) void gemm_o64(
    const ushort_t* __restrict__ A, const ushort_t* __restrict__ W,
    const float* __restrict__ bias, float* __restrict__ C) {
  constexpr int N = 1024, K = 1024;
  __shared__ alignas(16) ushort_t As[64 * 32];
  __shared__ alignas(16) ushort_t Bs[128 * 32];
  const int tid = threadIdx.x;
  const int w = tid >> 6, l = tid & 63, quad = l >> 4, li = l & 15;
  const int m0 = blockIdx.x * 64, n0 = blockIdx.y * 128;  // x = m-tile (XCD)
  const int wm = (w >> 1) * 32, wn = (w & 1) * 64;

  // staging: A 64x32 = 4 calls (1/wave); B 128x32 = 8 calls (2/wave)
  const int lofA = w * 512 + l * 8;
  const int rA = lofA >> 5, cA = lofA & 31;
  const int lofB0 = (w * 2 + 0) * 512 + l * 8;
  const int lofB1 = (w * 2 + 1) * 512 + l * 8;
  const int rB0 = lofB0 >> 5, cB0 = lofB0 & 31;
  const int rB1 = lofB1 >> 5, cB1 = lofB1 & 31;
  const ushort_t* gA = A + (size_t)(m0 + rA) * K + cA;
  const ushort_t* gB0 = W + (size_t)(n0 + rB0) * K + cB0;
  const ushort_t* gB1 = W + (size_t)(n0 + rB1) * K + cB1;

  const floatx4 fzero = {0.0f, 0.0f, 0.0f, 0.0f};
  floatx4 acc[2][4];
#pragma unroll
  for (int i = 0; i < 2; ++i)
#pragma unroll
    for (int j = 0; j < 4; ++j) acc[i][j] = fzero;

  for (int k0 = 0; k0 < K; k0 += 32) {
    lds_load16(As + lofA, gA + k0);
    lds_load16(Bs + lofB0, gB0 + k0);
    lds_load16(Bs + lofB1, gB1 + k0);
    __syncthreads();
    bf16x8 af[2], bfr[4];
#pragma unroll
    for (int mi = 0; mi < 2; ++mi)
      af[mi] = *(const bf16x8*)(As + (wm + mi * 16 + li) * 32 + quad * 8);
#pragma unroll
    for (int ni = 0; ni < 4; ++ni)
      bfr[ni] = *(const bf16x8*)(Bs + (wn + ni * 16 + li) * 32 + quad * 8);
#pragma unroll
    for (int mi = 0; mi < 2; ++mi)
#pragma unroll
      for (int ni = 0; ni < 4; ++ni)
        acc[mi][ni] = mfma16(af[mi], bfr[ni], acc[mi][ni]);
    __syncthreads();
  }

#pragma unroll
  for (int ni = 0; ni < 4; ++ni) {
    const int col = n0 + wn + ni * 16 + li;
    const float bv = bias[col];
#pragma unroll
    for (int mi = 0; mi < 2; ++mi) {
#pragma unroll
      for (int r = 0; r < 4; ++r) {
        const int row = m0 + wm + mi * 16 + quad * 4 + r;
        C[(size_t)row * N + col] = acc[mi][ni][r] + bv;
      }
    }
  }
}

// ---------------------------------------------------------------------------
// Block-sparse flash attention, ds_write staging, no-max softmax (unchanged
// from R7 — passed at absmax 2.2e-3).
// Grid (hb=b*16+h : 32, qb : 32); 256 threads, 4 waves.
// ---------------------------------------------------------------------------
__global__ __launch_bounds__(256) void attn_kernel(
    const ushort_t* __restrict__ Q, const ushort_t* __restrict__ Kg,
    const ushort_t* __restrict__ Vtg, ushort_t* __restrict__ O) {
  __shared__ alignas(16) ushort_t Kls[64 * 72];   // 9 KB, padded stride 72
  __shared__ alignas(16) ushort_t Vls[64 * 72];   // 9 KB
  __shared__ alignas(16) ushort_t Ps[4][16 * 72]; // 9 KB, per-wave P transpose

  const int tid = threadIdx.x;
  const int w = tid >> 6, l = tid & 63, quad = l >> 4, li = l & 15;
  const int hb = blockIdx.x, qb = blockIdx.y;
  const int h = hb & 15, b = hb >> 4;
  const size_t qoff = (size_t)b * 2048 * 1024 + (size_t)h * 64;
  const size_t vtoff = (size_t)hb * 64 * 2048;

  // mask list -> 8 uniform regs; kb extracted by rolling byte shifts
  unsigned lw[8];
#pragma unroll
  for (int j = 0; j < 8; ++j) lw[j] = ((const unsigned*)(MP.list[qb]))[j];
  const int nact = MP.cnt[qb];
  auto roll = [&]() -> int {
    const int kb = (int)(lw[0] & 255u);
#pragma unroll
    for (int j = 0; j < 7; ++j) lw[j] = (lw[j] >> 8) | (lw[j + 1] << 24);
    lw[7] >>= 8;
    return kb;
  };

  // Q fragments (A-layout), pre-scaled by 2^-3 (exact in bf16)
  const int qrow = qb * 64 + w * 16 + li;
  bf16x8 aq0 = *(const bf16x8*)(Q + qoff + (size_t)qrow * 1024 + quad * 8);
  bf16x8 aq1 = *(const bf16x8*)(Q + qoff + (size_t)qrow * 1024 + 32 + quad * 8);
#pragma unroll
  for (int j = 0; j < 8; ++j) {
    aq0[j] = (__bf16)((float)aq0[j] * 0.125f);
    aq1[j] = (__bf16)((float)aq1[j] * 0.125f);
  }

  const floatx4 fzero = {0.0f, 0.0f, 0.0f, 0.0f};
  floatx4 o_acc[4];
  float lp[4];
#pragma unroll
  for (int nt = 0; nt < 4; ++nt) o_acc[nt] = fzero;
#pragma unroll
  for (int r = 0; r < 4; ++r) lp[r] = 0.0f;

  // staging geometry: thread handles rows r0 = w*16 + (l>>3), r1 = r0+8,
  // colblock cb = (l&7)*8; lanes 0..7 = one contiguous 128B run per row.
  const int r0 = w * 16 + (l >> 3);
  const int r1 = r0 + 8;
  const int cb = (l & 7) * 8;
  const ushort_t* kg0 = Kg + qoff + (size_t)r0 * 1024 + cb;
  const ushort_t* kg1 = Kg + qoff + (size_t)r1 * 1024 + cb;
  const ushort_t* vg0 = Vtg + vtoff + (size_t)r0 * 2048 + cb;
  const ushort_t* vg1 = Vtg + vtoff + (size_t)r1 * 2048 + cb;
  ushort_t* kd0 = Kls + r0 * 72 + cb;
  ushort_t* kd1 = Kls + r1 * 72 + cb;
  ushort_t* vd0 = Vls + r0 * 72 + cb;
  ushort_t* vd1 = Vls + r1 * 72 + cb;
  ushort_t* PsW = Ps[w];

  int kb = roll();
  {
    const u16x8 a0 = *(const u16x8*)(kg0 + (size_t)kb * 65536);
    const u16x8 a1 = *(const u16x8*)(kg1 + (size_t)kb * 65536);
    const u16x8 b0 = *(const u16x8*)(vg0 + kb * 64);
    const u16x8 b1 = *(const u16x8*)(vg1 + kb * 64);
    *(u16x8*)kd0 = a0; *(u16x8*)kd1 = a1;
    *(u16x8*)vd0 = b0; *(u16x8*)vd1 = b1;
  }

  for (int i = 0; i < nact; ++i) {
    const int kbn = (i + 1 < nact) ? roll() : 0;
    __syncthreads();  // staging visible to all waves

    // S = (Q/8) K^T  (C-layout: row q = quad*4+r, col key = nt*16+li)
    floatx4 s[4];
#pragma unroll
    for (int nt = 0; nt < 4; ++nt) {
      const bf16x8 bk0 = *(const bf16x8*)(Kls + (nt * 16 + li) * 72 + quad * 8);
      const bf16x8 bk1 = *(const bf16x8*)(Kls + (nt * 16 + li) * 72 + 32 + quad * 8);
      s[nt] = mfma16(aq1, bk1, mfma16(aq0, bk0, fzero));
    }

    // P = exp(S) — no max subtraction (unit-variance scores, fp32-safe);
    // accumulate per-lane denominator partials; P -> per-wave LDS (A-layout)
#pragma unroll
    for (int nt = 0; nt < 4; ++nt)
#pragma unroll
      for (int r = 0; r < 4; ++r) {
        const float e = __expf(s[nt][r]);
        lp[r] += e;
        PsW[(quad * 4 + r) * 72 + nt * 16 + li] = f2bf(e);
      }

    // O += P V  (P A-frag via per-wave LDS, in-order DS pipe, no barrier)
#pragma unroll
    for (int c = 0; c < 2; ++c) {
      const bf16x8 pa = *(const bf16x8*)(PsW + li * 72 + c * 32 + quad * 8);
#pragma unroll
      for (int nt = 0; nt < 4; ++nt) {
        const bf16x8 vb = *(const bf16x8*)(Vls + (nt * 16 + li) * 72 + c * 32 + quad * 8);
        o_acc[nt] = mfma16(pa, vb, o_acc[nt]);
      }
    }

    __syncthreads();  // all waves done reading Kls/Vls
    if (i + 1 < nact) {
      const u16x8 a0 = *(const u16x8*)(kg0 + (size_t)kbn * 65536);
      const u16x8 a1 = *(const u16x8*)(kg1 + (size_t)kbn * 65536);
      const u16x8 b0 = *(const u16x8*)(vg0 + kbn * 64);
      const u16x8 b1 = *(const u16x8*)(vg1 + kbn * 64);
      *(u16x8*)kd0 = a0; *(u16x8*)kd1 = a1;
      *(u16x8*)vd0 = b0; *(u16x8*)vd1 = b1;
    }
  }

  // denominator: reduce the 16 lanes holding each row's column partials
#pragma unroll
  for (int stp = 1; stp <= 8; stp <<= 1)
#pragma unroll
    for (int r = 0; r < 4; ++r) lp[r] += __shfl_xor(lp[r], stp);

  // epilogue: O[b][s][h*64+d] bf16
#pragma unroll
  for (int r = 0; r < 4; ++r) {
    const float rinv = 1.0f / lp[r];
#pragma unroll
    for (int nt = 0; nt < 4; ++nt) {
      const float ov = o_acc[nt][r] * rinv;
      O[qoff + (size_t)(qb * 64 + w * 16 + quad * 4 + r) * 1024 + nt * 16 + li] = f2bf(ov);
    }
  }
}

// ---------------------------------------------------------------------------
extern "C" void kernel_launch(void* const* d_in, const int* in_sizes, int n_in,
                              void* d_out, int out_size, void* d_ws, size_t ws_size,
                              hipStream_t stream) {
  const float* hs = (const float*)d_in[0];
  const float* wq = (const float*)d_in[1];
  const float* bq = (const float*)d_in[2];
  const float* wk = (const float*)d_in[3];
  const float* bk = (const float*)d_in[4];
  const float* wv = (const float*)d_in[5];
  const float* bv = (const float*)d_in[6];
  const float* wo = (const float*)d_in[7];
  const float* bo = (const float*)d_in[8];
  float* out = (float*)d_out;

  char* ws = (char*)d_ws;
  ushort_t* hs_bf = (ushort_t*)(ws);                 // 8 MB; reused as attn out
  ushort_t* wq_bf = (ushort_t*)(ws + (8ull << 20));  // 2 MB each
  ushort_t* wk_bf = (ushort_t*)(ws + (10ull << 20));
  ushort_t* wv_bf = (ushort_t*)(ws + (12ull << 20));
  ushort_t* wo_bf = (ushort_t*)(ws + (14ull << 20));
  ushort_t* Qb = (ushort_t*)(ws + (16ull << 20));    // 8 MB each
  ushort_t* Kb = (ushort_t*)(ws + (24ull << 20));
  ushort_t* Vt = (ushort_t*)(ws + (32ull << 20));    // transposed V
  ushort_t* AO = hs_bf;  // hs_bf dead after QKV GEMM

  cvt_all<<<8192, 256, 0, stream>>>(hs, wq, wk, wv, wo,
                                    hs_bf, wq_bf, wk_bf, wv_bf, wo_bf);

  dim3 gq(32, 8, 3);  // x = m-tile (XCD-local A patch), y = n-tile, z = matrix
  gemm_qkv<<<gq, 256, 0, stream>>>(hs_bf, wq_bf, wk_bf, wv_bf, bq, bk, bv, Qb, Kb, Vt);

  dim3 ga(32, 32, 1);  // x = b*16+h (XCD-resident K/V), y = qb
  attn_kernel<<<ga, 256, 0, stream>>>(Qb, Kb, Vt, AO);

  dim3 go(64, 8, 1);   // x = m-tile, y = n-tile; 512 wgs = 2 wgs/CU
  gemm_o64<<<go, 256, 0, stream>>>(AO, wo_bf, bo, out);
}